// Round 7
// baseline (225.383 us; speedup 1.0000x reference)
//
#include <hip/hip_runtime.h>
#include <hip/hip_bf16.h>
#include <stdint.h>

// ---------------------------------------------------------------------------
// O = softmax(q_n . k_n^T) @ keys_raw   (N=65536, K=4096, D=128)
// 32x32x16 MFMA, transposed scheme: S^T = Kn.Qn^T, O^T = V^T.P^T; pi folded
// into vtf packing so S^T output regs ARE the PV B-fragment after exp+pack.
// R11: occupancy doubling via in-block K-split. Occupancy was pinned at
// 2 waves/SIMD by N/32rows = 2048 waves; now 512-thr blocks = 8 waves =
// 4 q-subtiles x 2 KEY-HALVES. Each wave: 32 q-rows x 2048 keys, 64 tiles of
// 32 keys (knf/vtf are linear in 8KB 32-key units by construction). LDS =
// 2 streams x (2x8K K + 2x8K V) = 64KB, grid 512 -> 2 blocks/CU = 16
// waves/CU = 4 waves/SIMD. Wave-pair merge of acc+den via LDS at the end.
// Per-wave state minimized for the 128-VGPR cap: no Sa/Sb exp-shift (cross-
// wave overlap at 4 waves/SIMD replaces it), no persistent Zf, pf[2],
// manual-RTNE pack (bit-identical to header minus NaN branch; R10 showed
// v_cvt_pk_bf16_f32 is NOT RTNE -- do not use it).
// Loop order per iter: PV(it-1) [old pf] -> S(it) -> exp(it)->pf.
//   knf blob: 32-key tile j occupies bytes [j*8192,(j+1)*8192): ds*1024+l*16
//   vtf blob: tile j: (sl*4+db2)*1024 + l*16
// ---------------------------------------------------------------------------

typedef __attribute__((ext_vector_type(8))) short bf16x8;
typedef __attribute__((ext_vector_type(16))) float f32x16;

#define MFMA32(a, b, c) __builtin_amdgcn_mfma_f32_32x32x16_bf16(a, b, c, 0, 0, 0)
#define ASYNC_CP16(gsrc, ldst)                                                  \
  __builtin_amdgcn_global_load_lds(                                             \
      (const __attribute__((address_space(1))) void*)(gsrc),                    \
      (__attribute__((address_space(3))) void*)(ldst), 16, 0, 0)

__device__ __forceinline__ unsigned pkbf(float lo, float hi) {
  union { __hip_bfloat162 h2; unsigned u; } v;
  v.h2 = __float22bfloat162_rn(float2{lo, hi});
  return v.u;
}

// manual RTNE pack: identical to header path minus NaN branch (inputs are
// exp2 outputs: finite, positive -- never NaN). R10 ERRATA: the HW
// v_cvt_pk_bf16_f32 is NOT round-to-nearest-even; it biased P low and failed
// absmax (5e-4 vs 2.9e-5). This is the correct fast pack (~8 VALU/pair).
__device__ __forceinline__ unsigned pkbf_fast(float lo, float hi) {
  union { float f; unsigned u; } a{lo}, b{hi};
  const unsigned ra = a.u + 0x7FFFu + ((a.u >> 16) & 1u);
  const unsigned rb = b.u + 0x7FFFu + ((b.u >> 16) & 1u);
  return (rb & 0xFFFF0000u) | (ra >> 16);
}

// ---------------- prep_k: fragment-pack Kn (normalized) and V^T (raw) -------
// One block per 32-key subtile: blockIdx.x = j, grid = K/32 = 128. (R9 ver.)
__global__ __launch_bounds__(256) void prep_k(const float* __restrict__ k,
                                              char* __restrict__ knf,
                                              char* __restrict__ vtf, int K) {
  __shared__ float sRaw[32 * 132];
  __shared__ float sScale[32];
  const int tid = threadIdx.x;
  const int kbase = blockIdx.x * 32;   // 32 keys per block
  {
    const int key_loc = tid >> 3, part = tid & 7;
    const float* src = k + (size_t)(kbase + key_loc) * 128 + part * 4;
    float4 f[4];
    float ss = 0.f;
#pragma unroll
    for (int i = 0; i < 4; ++i) {
      f[i] = *(const float4*)(src + i * 32);
      ss += f[i].x * f[i].x + f[i].y * f[i].y + f[i].z * f[i].z + f[i].w * f[i].w;
    }
    ss += __shfl_xor(ss, 1);
    ss += __shfl_xor(ss, 2);
    ss += __shfl_xor(ss, 4);
    float* dst = sRaw + key_loc * 132 + part * 4;
#pragma unroll
    for (int i = 0; i < 4; ++i) *(float4*)(dst + i * 32) = f[i];
    if (part == 0) sScale[key_loc] = ss > 0.f ? rsqrtf(ss) : 0.f;
  }
  __syncthreads();

#pragma unroll
  for (int r = 0; r < 2; ++r) {
    const int c2 = r * 256 + tid;
    const int ds = c2 >> 6, l = c2 & 63;
    const int h5 = l >> 5, c32 = l & 31;
    const float sc = sScale[c32];
    const float* p = sRaw + c32 * 132 + ds * 16 + h5 * 8;
    uint4 w;
    w.x = pkbf(p[0] * sc, p[1] * sc);
    w.y = pkbf(p[2] * sc, p[3] * sc);
    w.z = pkbf(p[4] * sc, p[5] * sc);
    w.w = pkbf(p[6] * sc, p[7] * sc);
    *(uint4*)(knf + ((size_t)blockIdx.x * 512 + c2) * 16) = w;
  }
#pragma unroll
  for (int r = 0; r < 2; ++r) {
    const int c2 = r * 256 + tid;
    const int sl = c2 >> 8, db2 = (c2 >> 6) & 3, l = c2 & 63;
    const int h5 = l >> 5, c32 = l & 31;
    const int d = db2 * 32 + c32;
    const int kb = sl * 8 + h5 * 4;
    float f[8];
#pragma unroll
    for (int j = 0; j < 8; ++j)
      f[j] = sRaw[(kb + (j & 3) + (j >> 2) * 16) * 132 + d];
    uint4 w;
    w.x = pkbf(f[0], f[1]);
    w.y = pkbf(f[2], f[3]);
    w.z = pkbf(f[4], f[5]);
    w.w = pkbf(f[6], f[7]);
    *(uint4*)(vtf + ((size_t)blockIdx.x * 512 + c2) * 16) = w;
  }
}

// ----------------------------- fused attention ------------------------------
// 512 thr = 8 waves: wave = qsub(0..3) + 4*h(key-half). Grid N/128 = 512.
// LDS 64KB total: 2 blocks/CU -> 16 waves/CU -> 4 waves/SIMD.
__global__ __launch_bounds__(512, 4) void attn_main(
    const float* __restrict__ q, const char* __restrict__ knf,
    const char* __restrict__ vtf, float* __restrict__ out, int K) {
  __shared__ __align__(16) char smem[65536];
  const int tid = threadIdx.x;
  const int wave = tid >> 6, lane = tid & 63;
  const int qsub = wave & 3, h = wave >> 2;
  const int h5 = lane >> 5, c32 = lane & 31;
  const int qrow0 = blockIdx.x * 128 + qsub * 32;
  char* sKh = smem + h * 16384;            // 2 bufs x 8KB, stream h
  char* sVh = smem + 32768 + h * 16384;    // 2 bufs x 8KB, stream h

  // ---- Q: load row (qrow0+c32), normalize, fold log2e, pack B-fragments ---
  bf16x8 qf[8];
  {
    const float* qr = q + (size_t)(qrow0 + c32) * 128;
    float f[64];
    float ss = 0.f;
#pragma unroll
    for (int ds = 0; ds < 8; ++ds) {
      const float4 a = *(const float4*)(qr + ds * 16 + h5 * 8);
      const float4 b = *(const float4*)(qr + ds * 16 + h5 * 8 + 4);
      f[ds * 8 + 0] = a.x; f[ds * 8 + 1] = a.y; f[ds * 8 + 2] = a.z; f[ds * 8 + 3] = a.w;
      f[ds * 8 + 4] = b.x; f[ds * 8 + 5] = b.y; f[ds * 8 + 6] = b.z; f[ds * 8 + 7] = b.w;
    }
#pragma unroll
    for (int i = 0; i < 64; ++i) ss += f[i] * f[i];
    ss += __shfl_xor(ss, 32);
    const float sc = (ss > 0.f ? rsqrtf(ss) : 0.f) * 1.44269504f;
#pragma unroll
    for (int ds = 0; ds < 8; ++ds) {
      union { unsigned u[4]; bf16x8 v; } t;
#pragma unroll
      for (int p = 0; p < 4; ++p)
        t.u[p] = pkbf(f[ds * 8 + 2 * p] * sc, f[ds * 8 + 2 * p + 1] * sc);
      qf[ds] = t.v;
    }
  }

  f32x16 acc[4];
#pragma unroll
  for (int db2 = 0; db2 < 4; ++db2)
#pragma unroll
    for (int r = 0; r < 16; ++r) acc[db2][r] = 0.f;
  float den = 0.f;

  union pfu { unsigned u[4]; bf16x8 v; };
  pfu pf[2];            // P B-fragments of the previous tile

  const int nIter = K >> 6;   // (K/2 keys)/32 per tile = 64 iters per stream
  // per-wave staging bases: stream h, this wave stages chunks qsub*2+{0,1}
  const char* knfW = knf + ((size_t)h * nIter) * 8192 + qsub * 2048 + lane * 16;
  const char* vtfW = vtf + ((size_t)h * nIter) * 8192 + qsub * 2048 + lane * 16;
  char* dK = sKh + qsub * 2048;
  char* dV = sVh + qsub * 2048;

  auto stageK = [&](int it, int buf) {
#pragma unroll
    for (int i = 0; i < 2; ++i)
      ASYNC_CP16(knfW + (size_t)it * 8192 + i * 1024, dK + buf * 8192 + i * 1024);
  };
  auto stageV = [&](int it, int buf) {
#pragma unroll
    for (int i = 0; i < 2; ++i)
      ASYNC_CP16(vtfW + (size_t)it * 8192 + i * 1024, dV + buf * 8192 + i * 1024);
  };

  // S^T(32k x 32q) = Kn_tile . Qn^T : one chain of 8 MFMAs; s zero-init
  // per iter (no persistent Zf register block).
  auto computeS = [&](int buf, f32x16& S) {
    f32x16 s;
#pragma unroll
    for (int r = 0; r < 16; ++r) s[r] = 0.f;
#pragma unroll
    for (int ds = 0; ds < 8; ++ds) {
      const bf16x8 kf = *(const bf16x8*)(sKh + buf * 8192 + ds * 1024 + lane * 16);
      s = MFMA32(kf, qf[ds], s);
    }
    S = s;
  };

  // exp(S) -> pf (B-frags consumed by NEXT iter's PV), den accumulate.
  auto doExp = [&](const f32x16& S) {
#pragma unroll
    for (int sl = 0; sl < 2; ++sl) {
      float e[8];
#pragma unroll
      for (int j = 0; j < 8; ++j) {
        const int rr = sl * 4 + (j & 3) + (j >> 2) * 8;
        e[j] = __builtin_amdgcn_exp2f(S[rr]);
      }
      den += ((e[0] + e[1]) + (e[2] + e[3])) + ((e[4] + e[5]) + (e[6] + e[7]));
#pragma unroll
      for (int j2 = 0; j2 < 4; ++j2)
        pf[sl].u[j2] = pkbf_fast(e[2 * j2], e[2 * j2 + 1]);
    }
  };

  // PV from LDS: 8 ds_read_b128 + 8 MFMAs in 4 acc chains; pf is from the
  // PREVIOUS iter -> independent of this iter's S/exp.
  auto doPV = [&](int buf) {
    const char* vb = sVh + buf * 8192 + lane * 16;
#pragma unroll
    for (int sl = 0; sl < 2; ++sl) {
      bf16x8 v0 = *(const bf16x8*)(vb + (sl * 4 + 0) * 1024);
      bf16x8 v1 = *(const bf16x8*)(vb + (sl * 4 + 1) * 1024);
      bf16x8 v2 = *(const bf16x8*)(vb + (sl * 4 + 2) * 1024);
      bf16x8 v3 = *(const bf16x8*)(vb + (sl * 4 + 3) * 1024);
      acc[0] = MFMA32(v0, pf[sl].v, acc[0]);
      acc[1] = MFMA32(v1, pf[sl].v, acc[1]);
      acc[2] = MFMA32(v2, pf[sl].v, acc[2]);
      acc[3] = MFMA32(v3, pf[sl].v, acc[3]);
    }
  };

  // ---- K-loop: iter it = {sync; stageK(it+1); stageV(it);
  //                         PV(it-1) [old pf]; S(it); exp(it)->pf} ----------
  f32x16 S;
  stageK(0, 0);
  stageV(0, 0);
  __syncthreads();            // K0, V0 landed
  stageK(1, 1);
  computeS(0, S);
  doExp(S);                   // pf <- exp(S(0))

  for (int it = 1; it < nIter; ++it) {
    const int buf = it & 1;
    __syncthreads();          // K(it), V(it) staged last iter... V(it-1) landed
    if (it + 1 < nIter) stageK(it + 1, buf ^ 1);
    stageV(it, buf);
    __builtin_amdgcn_s_setprio(1);
    doPV(buf ^ 1);            // PV(it-1) from sV[(it-1)&1], pf(it-1)
    computeS(buf, S);         // S(it)
    __builtin_amdgcn_s_setprio(0);
    doExp(S);                 // pf <- exp(S(it))
  }
  __syncthreads();            // V(nIter-1) landed
  doPV((nIter - 1) & 1);      // PV(63) from sV[1]

  // ---- wave-pair merge (h=1 -> h=0) via LDS, then h=0 epilogue ------------
  float* pair = (float*)(smem + qsub * 16384);
  __syncthreads();            // all waves done with sK/sV
  if (h == 1) pair[lane] = den;
  __syncthreads();
  if (h == 0) den += pair[lane];
  __syncthreads();
  if (h == 1) {
#pragma unroll
    for (int i = 0; i < 4; ++i)
#pragma unroll
      for (int p2 = 0; p2 < 4; ++p2) {
        float4 v;
        v.x = acc[i][p2 * 4 + 0]; v.y = acc[i][p2 * 4 + 1];
        v.z = acc[i][p2 * 4 + 2]; v.w = acc[i][p2 * 4 + 3];
        *(float4*)((char*)pair + (i * 4 + p2) * 1024 + lane * 16) = v;
      }
  }
  __syncthreads();
  if (h == 0) {
#pragma unroll
    for (int i = 0; i < 4; ++i)
#pragma unroll
      for (int p2 = 0; p2 < 4; ++p2) {
        const float4 v = *(const float4*)((char*)pair + (i * 4 + p2) * 1024 + lane * 16);
        acc[i][p2 * 4 + 0] += v.x; acc[i][p2 * 4 + 1] += v.y;
        acc[i][p2 * 4 + 2] += v.z; acc[i][p2 * 4 + 3] += v.w;
      }
    den += __shfl_xor(den, 32);
    const float rd = 1.0f / den;

    // epilogue: per-wave LDS transpose (XOR-swizzled) into own pair region
    float* wls = pair;        // 4KB scratch; pair data already consumed
#pragma unroll
    for (int db2 = 0; db2 < 4; ++db2) {
#pragma unroll
      for (int qd = 0; qd < 4; ++qd) {
        float4 v;
        v.x = acc[db2][qd * 4 + 0] * rd;
        v.y = acc[db2][qd * 4 + 1] * rd;
        v.z = acc[db2][qd * 4 + 2] * rd;
        v.w = acc[db2][qd * 4 + 3] * rd;
        *(float4*)(wls + c32 * 32 + (((h5 + 2 * qd) ^ (c32 & 7)) << 2)) = v;
      }
#pragma unroll
      for (int p = 0; p < 4; ++p) {
        const int ql = p * 8 + (lane >> 3);
        const int x = lane & 7;
        const float4 v = *(const float4*)(wls + ql * 32 + ((x ^ (ql & 7)) << 2));
        *(float4*)(out + (size_t)(qrow0 + ql) * 128 + db2 * 32 + x * 4) = v;
      }
    }
  }
}

// ---------------------------------------------------------------------------
extern "C" void kernel_launch(void* const* d_in, const int* in_sizes, int n_in,
                              void* d_out, int out_size, void* d_ws, size_t ws_size,
                              hipStream_t stream) {
  const float* q = (const float*)d_in[0];
  const float* k = (const float*)d_in[1];
  const int N = in_sizes[0] / 128;   // 65536
  const int K = in_sizes[1] / 128;   // 4096
  char* ws = (char*)d_ws;
  char* knf = ws;                          // K*256 B = 1 MB
  char* vtf = ws + (size_t)K * 256;        // 1 MB
  float* out = (float*)d_out;

  prep_k<<<dim3(K / 32), dim3(256), 0, stream>>>(k, knf, vtf, K);
  attn_main<<<dim3(N / 128), dim3(512), 0, stream>>>(q, knf, vtf, out, K);
}

// Round 9
// 208.444 us; speedup vs baseline: 1.0813x; 1.0813x over previous
//
#include <hip/hip_runtime.h>
#include <hip/hip_bf16.h>
#include <stdint.h>

// ---------------------------------------------------------------------------
// O = softmax(q_n . k_n^T) @ keys_raw   (N=65536, K=4096, D=128)
// 32x32x16 MFMA, transposed scheme: S^T = Kn.Qn^T, O^T = V^T.P^T; pi folded
// into vtf packing so S^T output regs ARE the PV B-fragment after exp+pack.
// R12 (resubmit; previous round died on container acquire, not the kernel):
// attn_main = exact R7/R9 structure (135.5us known-good; R11's K-split
// regressed: occupancy doubled to 39% but barrier-locked waves share phase ->
// no extra overlap, and 32-key tiles doubled barrier cost per MFMA). Single
// change vs R9: hot-path exp->pf pack uses manual-RTNE pkbf_fast (~5 ops/pair
// vs header ~12; NaN branch dropped -- exp2 output is never NaN). Correctness
// of this pack was proven in R11 (absmax 7.6e-6). R10 ERRATA stands:
// v_cvt_pk_bf16_f32 is NOT RTNE, do not use it.
//   knf blob: chunk c = blk32*512 + ds*64 + lane  (16B chunks)
//   vtf blob: chunk c = blk32*512 + sl*256 + db2*64 + lane (16B chunks)
// ---------------------------------------------------------------------------

typedef __attribute__((ext_vector_type(8))) short bf16x8;
typedef __attribute__((ext_vector_type(16))) float f32x16;

#define MFMA32(a, b, c) __builtin_amdgcn_mfma_f32_32x32x16_bf16(a, b, c, 0, 0, 0)
#define ASYNC_CP16(gsrc, ldst)                                                  \
  __builtin_amdgcn_global_load_lds(                                             \
      (const __attribute__((address_space(1))) void*)(gsrc),                    \
      (__attribute__((address_space(3))) void*)(ldst), 16, 0, 0)

__device__ __forceinline__ unsigned pkbf(float lo, float hi) {
  union { __hip_bfloat162 h2; unsigned u; } v;
  v.h2 = __float22bfloat162_rn(float2{lo, hi});
  return v.u;
}

// manual RTNE pack: identical rounding to the header path minus the NaN
// branch (inputs are exp2 outputs: finite, positive). Proven correct in R11.
__device__ __forceinline__ unsigned pkbf_fast(float lo, float hi) {
  union { float f; unsigned u; } a{lo}, b{hi};
  const unsigned ra = a.u + 0x7FFFu + ((a.u >> 16) & 1u);
  const unsigned rb = b.u + 0x7FFFu + ((b.u >> 16) & 1u);
  return (rb & 0xFFFF0000u) | (ra >> 16);
}

// ---------------- prep_k: fragment-pack Kn (normalized) and V^T (raw) -------
// One block per 32-key subtile: blockIdx.x = blk64*2 + t, grid = K/32 = 128.
__global__ __launch_bounds__(256) void prep_k(const float* __restrict__ k,
                                              char* __restrict__ knf,
                                              char* __restrict__ vtf, int K) {
  __shared__ float sRaw[32 * 132];
  __shared__ float sScale[32];
  const int tid = threadIdx.x;
  const int kbase = blockIdx.x * 32;   // 32 keys per block
  {
    // 8 threads per key; lane-consecutive float4 reads (coalesced).
    const int key_loc = tid >> 3, part = tid & 7;
    const float* src = k + (size_t)(kbase + key_loc) * 128 + part * 4;
    float4 f[4];
    float ss = 0.f;
#pragma unroll
    for (int i = 0; i < 4; ++i) {
      f[i] = *(const float4*)(src + i * 32);
      ss += f[i].x * f[i].x + f[i].y * f[i].y + f[i].z * f[i].z + f[i].w * f[i].w;
    }
    ss += __shfl_xor(ss, 1);
    ss += __shfl_xor(ss, 2);
    ss += __shfl_xor(ss, 4);
    float* dst = sRaw + key_loc * 132 + part * 4;
#pragma unroll
    for (int i = 0; i < 4; ++i) *(float4*)(dst + i * 32) = f[i];
    if (part == 0) sScale[key_loc] = ss > 0.f ? rsqrtf(ss) : 0.f;
  }
  __syncthreads();

  // knf: 512 chunks for this subtile; global chunk = blockIdx.x*512 + c2
#pragma unroll
  for (int r = 0; r < 2; ++r) {
    const int c2 = r * 256 + tid;
    const int ds = c2 >> 6, l = c2 & 63;
    const int h5 = l >> 5, c32 = l & 31;
    const float sc = sScale[c32];
    const float* p = sRaw + c32 * 132 + ds * 16 + h5 * 8;
    uint4 w;
    w.x = pkbf(p[0] * sc, p[1] * sc);
    w.y = pkbf(p[2] * sc, p[3] * sc);
    w.z = pkbf(p[4] * sc, p[5] * sc);
    w.w = pkbf(p[6] * sc, p[7] * sc);
    *(uint4*)(knf + ((size_t)blockIdx.x * 512 + c2) * 16) = w;
  }
  // vtf: 512 chunks; c2 = sl*256 + db2*64 + l
#pragma unroll
  for (int r = 0; r < 2; ++r) {
    const int c2 = r * 256 + tid;
    const int sl = c2 >> 8, db2 = (c2 >> 6) & 3, l = c2 & 63;
    const int h5 = l >> 5, c32 = l & 31;
    const int d = db2 * 32 + c32;
    const int kb = sl * 8 + h5 * 4;
    float f[8];
#pragma unroll
    for (int j = 0; j < 8; ++j)
      f[j] = sRaw[(kb + (j & 3) + (j >> 2) * 16) * 132 + d];
    uint4 w;
    w.x = pkbf(f[0], f[1]);
    w.y = pkbf(f[2], f[3]);
    w.z = pkbf(f[4], f[5]);
    w.w = pkbf(f[6], f[7]);
    *(uint4*)(vtf + ((size_t)blockIdx.x * 512 + c2) * 16) = w;
  }
}

// ----------------------------- fused attention ------------------------------
// 256 thr = 4 waves x 32 q-rows; grid N/128 = 512. LDS 64KB: 2 blocks/CU.
// (exact R7 structure -- known 135.5us -- with fast exp->pf packs)
__global__ __launch_bounds__(256, 2) void attn_main(
    const float* __restrict__ q, const char* __restrict__ knf,
    const char* __restrict__ vtf, float* __restrict__ out, int K) {
  __shared__ __align__(16) char sK[2][16384];
  __shared__ __align__(16) char sV[2][16384];
  const int tid = threadIdx.x;
  const int wave = tid >> 6, lane = tid & 63;
  const int h5 = lane >> 5, c32 = lane & 31;
  const int qrow0 = blockIdx.x * 128 + wave * 32;

  // ---- Q: load row (qrow0+c32), normalize, fold log2e, pack B-fragments ---
  bf16x8 qf[8];
  {
    const float* qr = q + (size_t)(qrow0 + c32) * 128;
    float f[64];
    float ss = 0.f;
#pragma unroll
    for (int ds = 0; ds < 8; ++ds) {
      const float4 a = *(const float4*)(qr + ds * 16 + h5 * 8);
      const float4 b = *(const float4*)(qr + ds * 16 + h5 * 8 + 4);
      f[ds * 8 + 0] = a.x; f[ds * 8 + 1] = a.y; f[ds * 8 + 2] = a.z; f[ds * 8 + 3] = a.w;
      f[ds * 8 + 4] = b.x; f[ds * 8 + 5] = b.y; f[ds * 8 + 6] = b.z; f[ds * 8 + 7] = b.w;
    }
#pragma unroll
    for (int i = 0; i < 64; ++i) ss += f[i] * f[i];
    ss += __shfl_xor(ss, 32);
    const float sc = (ss > 0.f ? rsqrtf(ss) : 0.f) * 1.44269504f;
#pragma unroll
    for (int ds = 0; ds < 8; ++ds) {
      union { unsigned u[4]; bf16x8 v; } t;
#pragma unroll
      for (int p = 0; p < 4; ++p)
        t.u[p] = pkbf(f[ds * 8 + 2 * p] * sc, f[ds * 8 + 2 * p + 1] * sc);
      qf[ds] = t.v;
    }
  }

  f32x16 acc[4];
#pragma unroll
  for (int db2 = 0; db2 < 4; ++db2)
#pragma unroll
    for (int r = 0; r < 16; ++r) acc[db2][r] = 0.f;
  float den = 0.f;
  f32x16 Zf;
#pragma unroll
  for (int r = 0; r < 16; ++r) Zf[r] = 0.f;

  union pfu { unsigned u[4]; bf16x8 v; };
  pfu pf[4];            // P fragments (B-frags for PV), refreshed each sub-iter
  f32x16 Sa[2], Sb[2];  // S ping-pong: even tiles -> Sa, odd tiles -> Sb

  const int nIter = K >> 6;   // 64 iters of 64 keys (even, >= 4)

  auto stageK = [&](int it, int buf) {
#pragma unroll
    for (int i = 0; i < 4; ++i)
      ASYNC_CP16(knf + (size_t)it * 16384 + (wave * 4 + i) * 1024 + lane * 16,
                 sK[buf] + (wave * 4 + i) * 1024);
  };
  auto stageV = [&](int it, int buf) {
#pragma unroll
    for (int i = 0; i < 4; ++i)
      ASYNC_CP16(vtf + (size_t)it * 16384 + (wave * 4 + i) * 1024 + lane * 16,
                 sV[buf] + (wave * 4 + i) * 1024);
  };

  // S^T = Kn . Qn^T for tile in sK[buf] (2 independent chains of 8)
  auto computeS = [&](int buf, f32x16* S) {
#pragma unroll
    for (int t = 0; t < 2; ++t) {
      f32x16 s;
#pragma unroll
      for (int ds = 0; ds < 8; ++ds) {
        const bf16x8 kf = *(const bf16x8*)(sK[buf] + (t * 8 + ds) * 1024 + lane * 16);
        s = MFMA32(kf, qf[ds], (ds == 0) ? Zf : s);
      }
      S[t] = s;
    }
  };

  // exp(S_prev) -> pf (B-fragments for this sub-iter's PV), den accumulate.
  // Independent of the S currently being built -> co-issues with MFMA chain.
  // Packs via manual-RTNE pkbf_fast (hot path).
  auto doExp = [&](const f32x16* S) {
#pragma unroll
    for (int s = 0; s < 4; ++s) {
      const int t = s >> 1, w = s & 1;
      float e[8];
#pragma unroll
      for (int j = 0; j < 8; ++j) {
        const int rr = w * 4 + (j & 3) + (j >> 2) * 8;
        e[j] = __builtin_amdgcn_exp2f(S[t][rr]);
      }
      den += ((e[0] + e[1]) + (e[2] + e[3])) + ((e[4] + e[5]) + (e[6] + e[7]));
#pragma unroll
      for (int j2 = 0; j2 < 4; ++j2)
        pf[s].u[j2] = pkbf_fast(e[2 * j2], e[2 * j2 + 1]);
    }
  };

  // PV from LDS: 16 ds_read_b128 at uniform base + imm offsets, 16 MFMAs in
  // 4 independent acc chains. Compiler interleaves reads/MFMAs (lgkmcnt).
  auto doPV = [&](int buf) {
    const char* vb = sV[buf] + lane * 16;
#pragma unroll
    for (int s = 0; s < 4; ++s) {
      bf16x8 v0 = *(const bf16x8*)(vb + (s * 4 + 0) * 1024);
      bf16x8 v1 = *(const bf16x8*)(vb + (s * 4 + 1) * 1024);
      bf16x8 v2 = *(const bf16x8*)(vb + (s * 4 + 2) * 1024);
      bf16x8 v3 = *(const bf16x8*)(vb + (s * 4 + 3) * 1024);
      acc[0] = MFMA32(v0, pf[s].v, acc[0]);
      acc[1] = MFMA32(v1, pf[s].v, acc[1]);
      acc[2] = MFMA32(v2, pf[s].v, acc[2]);
      acc[3] = MFMA32(v3, pf[s].v, acc[3]);
    }
  };

  // ---- pipelined K-loop ----------------------------------------------------
  // iter it: {sync; stageK(it+1); stageV(it); S(it) || exp(S(it-1)); PV(it-1)}
  // V(it) lands by the barrier of iter it+1, exactly when PV(it) needs it.
  stageK(0, 0);
  stageV(0, 0);
  __syncthreads();            // K0, V0 landed
  stageK(1, 1);
  computeS(0, Sa);            // S(0)

  // iter 1 (peeled):
  __syncthreads();            // K1 landed; tile-0 ds_reads drained
  stageK(2, 0);
  stageV(1, 1);
  __builtin_amdgcn_s_setprio(1);
  computeS(1, Sb);            // S(1)
  doExp(Sa);                  // pf <- exp(S(0))
  doPV(0);                    // V(0) from sV[0]
  __builtin_amdgcn_s_setprio(0);

  for (int itp = 2; itp < nIter; itp += 2) {
    // ---- even iter itp: cur -> Sa, prev = Sb, PV(itp-1) from sV[1] ----
    __syncthreads();          // K(itp), V(itp-1) landed; old reads drained
    stageK(itp + 1, 1);
    stageV(itp, 0);
    __builtin_amdgcn_s_setprio(1);
    computeS(0, Sa);
    doExp(Sb);                // pf <- exp(S(itp-1))
    doPV(1);
    __builtin_amdgcn_s_setprio(0);

    // ---- odd iter itp+1: cur -> Sb, prev = Sa, PV(itp) from sV[0] ----
    __syncthreads();          // K(itp+1), V(itp) landed
    if (itp + 2 < nIter) stageK(itp + 2, 0);
    stageV(itp + 1, 1);
    __builtin_amdgcn_s_setprio(1);
    computeS(1, Sb);
    doExp(Sa);                // pf <- exp(S(itp))
    doPV(0);
    __builtin_amdgcn_s_setprio(0);
  }

  // drain: V(nIter-1) was staged at iter nIter-1; barrier to land it.
  __syncthreads();
  doExp(Sb);                  // pf <- exp(S(nIter-1))
  doPV(1);                    // (nIter-1) odd -> sV[1]

  den += __shfl_xor(den, 32);
  const float rd = 1.0f / den;

  // ---- epilogue: per-wave LDS transpose (XOR-swizzled), coalesced stores ---
  __syncthreads();            // all waves done with sK/sV
  float* wls = (float*)(&sK[0][0] + wave * 4096);   // 32 q-rows x 32 floats
#pragma unroll
  for (int db2 = 0; db2 < 4; ++db2) {
#pragma unroll
    for (int qd = 0; qd < 4; ++qd) {
      float4 v;
      v.x = acc[db2][qd * 4 + 0] * rd;
      v.y = acc[db2][qd * 4 + 1] * rd;
      v.z = acc[db2][qd * 4 + 2] * rd;
      v.w = acc[db2][qd * 4 + 3] * rd;
      *(float4*)(wls + c32 * 32 + (((h5 + 2 * qd) ^ (c32 & 7)) << 2)) = v;
    }
#pragma unroll
    for (int p = 0; p < 4; ++p) {
      const int ql = p * 8 + (lane >> 3);
      const int x = lane & 7;
      const float4 v = *(const float4*)(wls + ql * 32 + ((x ^ (ql & 7)) << 2));
      *(float4*)(out + (size_t)(qrow0 + ql) * 128 + db2 * 32 + x * 4) = v;
    }
  }
}

// ---------------------------------------------------------------------------
extern "C" void kernel_launch(void* const* d_in, const int* in_sizes, int n_in,
                              void* d_out, int out_size, void* d_ws, size_t ws_size,
                              hipStream_t stream) {
  const float* q = (const float*)d_in[0];
  const float* k = (const float*)d_in[1];
  const int N = in_sizes[0] / 128;   // 65536
  const int K = in_sizes[1] / 128;   // 4096
  char* ws = (char*)d_ws;
  char* knf = ws;                          // K*256 B = 1 MB
  char* vtf = ws + (size_t)K * 256;        // 1 MB
  float* out = (float*)d_out;

  prep_k<<<dim3(K / 32), dim3(256), 0, stream>>>(k, knf, vtf, K);
  attn_main<<<dim3(N / 128), dim3(256), 0, stream>>>(q, knf, vtf, out, K);
}

// Round 10
// 206.774 us; speedup vs baseline: 1.0900x; 1.0081x over previous
//
#include <hip/hip_runtime.h>
#include <hip/hip_bf16.h>
#include <stdint.h>

// ---------------------------------------------------------------------------
// O = softmax(q_n . k_n^T) @ keys_raw   (N=65536, K=4096, D=128)
// 32x32x16 MFMA, transposed scheme: S^T = Kn.Qn^T, O^T = V^T.P^T; pi folded
// into vtf packing so S^T output regs ARE the PV B-fragment after exp+pack.
// R13: hybrid V to relieve LDS bandwidth. Pipe budget per CU per 64-key iter:
// MFMA 2163cy, LDS-read 2048-3072cy (8 waves x 32 ds_read_b128 -- co-equal
// bottleneck, conflict-free so invisible in counters), L2 ~860cy. V frags
// s=0,1 stay in LDS (sV now 2x8KB); s=2,3 load per-wave from L2 into regs,
// ISSUED AT ITERATION TOP (~1500cy before doPV consumes them -- R5/R6's
// mid-PV issue left only ~128cy cover, which is why full-L2-V lost). LDS
// reads drop 32->24KB/wave/iter; vtf staging halves. pkbf reverted to header
// (R12's manual-RTNE pack was neutral-to-negative; R10 ERRATA stands:
// v_cvt_pk_bf16_f32 is NOT RTNE, do not use it).
// Occupancy is grid-capped at 2 waves/SIMD (2048 waves total); 16-row waves
// would double LDS bytes/row -- ruled out by the same arithmetic.
//   knf blob: chunk c = blk32*512 + ds*64 + lane  (16B chunks)
//   vtf blob: chunk c = blk32*512 + sl*256 + db2*64 + lane (16B chunks)
// ---------------------------------------------------------------------------

typedef __attribute__((ext_vector_type(8))) short bf16x8;
typedef __attribute__((ext_vector_type(16))) float f32x16;

#define MFMA32(a, b, c) __builtin_amdgcn_mfma_f32_32x32x16_bf16(a, b, c, 0, 0, 0)
#define ASYNC_CP16(gsrc, ldst)                                                  \
  __builtin_amdgcn_global_load_lds(                                             \
      (const __attribute__((address_space(1))) void*)(gsrc),                    \
      (__attribute__((address_space(3))) void*)(ldst), 16, 0, 0)

__device__ __forceinline__ unsigned pkbf(float lo, float hi) {
  union { __hip_bfloat162 h2; unsigned u; } v;
  v.h2 = __float22bfloat162_rn(float2{lo, hi});
  return v.u;
}

// ---------------- prep_k: fragment-pack Kn (normalized) and V^T (raw) -------
// One block per 32-key subtile: grid = K/32 = 128. (R9 version, unchanged)
__global__ __launch_bounds__(256) void prep_k(const float* __restrict__ k,
                                              char* __restrict__ knf,
                                              char* __restrict__ vtf, int K) {
  __shared__ float sRaw[32 * 132];
  __shared__ float sScale[32];
  const int tid = threadIdx.x;
  const int kbase = blockIdx.x * 32;   // 32 keys per block
  {
    // 8 threads per key; lane-consecutive float4 reads (coalesced).
    const int key_loc = tid >> 3, part = tid & 7;
    const float* src = k + (size_t)(kbase + key_loc) * 128 + part * 4;
    float4 f[4];
    float ss = 0.f;
#pragma unroll
    for (int i = 0; i < 4; ++i) {
      f[i] = *(const float4*)(src + i * 32);
      ss += f[i].x * f[i].x + f[i].y * f[i].y + f[i].z * f[i].z + f[i].w * f[i].w;
    }
    ss += __shfl_xor(ss, 1);
    ss += __shfl_xor(ss, 2);
    ss += __shfl_xor(ss, 4);
    float* dst = sRaw + key_loc * 132 + part * 4;
#pragma unroll
    for (int i = 0; i < 4; ++i) *(float4*)(dst + i * 32) = f[i];
    if (part == 0) sScale[key_loc] = ss > 0.f ? rsqrtf(ss) : 0.f;
  }
  __syncthreads();

  // knf: 512 chunks for this subtile; global chunk = blockIdx.x*512 + c2
#pragma unroll
  for (int r = 0; r < 2; ++r) {
    const int c2 = r * 256 + tid;
    const int ds = c2 >> 6, l = c2 & 63;
    const int h5 = l >> 5, c32 = l & 31;
    const float sc = sScale[c32];
    const float* p = sRaw + c32 * 132 + ds * 16 + h5 * 8;
    uint4 w;
    w.x = pkbf(p[0] * sc, p[1] * sc);
    w.y = pkbf(p[2] * sc, p[3] * sc);
    w.z = pkbf(p[4] * sc, p[5] * sc);
    w.w = pkbf(p[6] * sc, p[7] * sc);
    *(uint4*)(knf + ((size_t)blockIdx.x * 512 + c2) * 16) = w;
  }
  // vtf: 512 chunks; c2 = sl*256 + db2*64 + l
#pragma unroll
  for (int r = 0; r < 2; ++r) {
    const int c2 = r * 256 + tid;
    const int sl = c2 >> 8, db2 = (c2 >> 6) & 3, l = c2 & 63;
    const int h5 = l >> 5, c32 = l & 31;
    const int d = db2 * 32 + c32;
    const int kb = sl * 8 + h5 * 4;
    float f[8];
#pragma unroll
    for (int j = 0; j < 8; ++j)
      f[j] = sRaw[(kb + (j & 3) + (j >> 2) * 16) * 132 + d];
    uint4 w;
    w.x = pkbf(f[0], f[1]);
    w.y = pkbf(f[2], f[3]);
    w.z = pkbf(f[4], f[5]);
    w.w = pkbf(f[6], f[7]);
    *(uint4*)(vtf + ((size_t)blockIdx.x * 512 + c2) * 16) = w;
  }
}

// ----------------------------- fused attention ------------------------------
// 256 thr = 4 waves x 32 q-rows; grid N/128 = 512. LDS 48KB: 2 blocks/CU.
__global__ __launch_bounds__(256, 2) void attn_main(
    const float* __restrict__ q, const char* __restrict__ knf,
    const char* __restrict__ vtf, float* __restrict__ out, int K) {
  __shared__ __align__(16) char sK[2][16384];
  __shared__ __align__(16) char sV[2][8192];   // V frags s=0,1 only
  const int tid = threadIdx.x;
  const int wave = tid >> 6, lane = tid & 63;
  const int h5 = lane >> 5, c32 = lane & 31;
  const int qrow0 = blockIdx.x * 128 + wave * 32;

  // ---- Q: load row (qrow0+c32), normalize, fold log2e, pack B-fragments ---
  bf16x8 qf[8];
  {
    const float* qr = q + (size_t)(qrow0 + c32) * 128;
    float f[64];
    float ss = 0.f;
#pragma unroll
    for (int ds = 0; ds < 8; ++ds) {
      const float4 a = *(const float4*)(qr + ds * 16 + h5 * 8);
      const float4 b = *(const float4*)(qr + ds * 16 + h5 * 8 + 4);
      f[ds * 8 + 0] = a.x; f[ds * 8 + 1] = a.y; f[ds * 8 + 2] = a.z; f[ds * 8 + 3] = a.w;
      f[ds * 8 + 4] = b.x; f[ds * 8 + 5] = b.y; f[ds * 8 + 6] = b.z; f[ds * 8 + 7] = b.w;
    }
#pragma unroll
    for (int i = 0; i < 64; ++i) ss += f[i] * f[i];
    ss += __shfl_xor(ss, 32);
    const float sc = (ss > 0.f ? rsqrtf(ss) : 0.f) * 1.44269504f;
#pragma unroll
    for (int ds = 0; ds < 8; ++ds) {
      union { unsigned u[4]; bf16x8 v; } t;
#pragma unroll
      for (int p = 0; p < 4; ++p)
        t.u[p] = pkbf(f[ds * 8 + 2 * p] * sc, f[ds * 8 + 2 * p + 1] * sc);
      qf[ds] = t.v;
    }
  }

  f32x16 acc[4];
#pragma unroll
  for (int db2 = 0; db2 < 4; ++db2)
#pragma unroll
    for (int r = 0; r < 16; ++r) acc[db2][r] = 0.f;
  float den = 0.f;
  f32x16 Zf;
#pragma unroll
  for (int r = 0; r < 16; ++r) Zf[r] = 0.f;

  union pfu { unsigned u[4]; bf16x8 v; };
  pfu pf[4];            // P fragments (B-frags for PV), refreshed each sub-iter
  f32x16 Sa[2], Sb[2];  // S ping-pong: even tiles -> Sa, odd tiles -> Sb
  bf16x8 vreg[8];       // V frags s=2,3 of the PV tile (from L2, issue-early)

  const int nIter = K >> 6;   // 64 iters of 64 keys (even, >= 4)

  auto stageK = [&](int it, int buf) {
#pragma unroll
    for (int i = 0; i < 4; ++i)
      ASYNC_CP16(knf + (size_t)it * 16384 + (wave * 4 + i) * 1024 + lane * 16,
                 sK[buf] + (wave * 4 + i) * 1024);
  };
  // stage only V chunks 0..7 (s=0,1): 2 chunks per wave
  auto stageV = [&](int it, int buf) {
#pragma unroll
    for (int i = 0; i < 2; ++i)
      ASYNC_CP16(vtf + (size_t)it * 16384 + (wave * 2 + i) * 1024 + lane * 16,
                 sV[buf] + (wave * 2 + i) * 1024);
  };
  // V frags s=2,3 (chunks 8..15) straight from L2 into registers; issued at
  // iteration top so computeS+doExp (~1500cy) covers L2 latency.
  auto loadV23 = [&](int m) {
    const char* vb = vtf + (size_t)m * 16384 + lane * 16;
#pragma unroll
    for (int i = 0; i < 8; ++i)
      vreg[i] = *(const bf16x8*)(vb + (8 + i) * 1024);
  };

  // S^T = Kn . Qn^T for tile in sK[buf] (2 independent chains of 8)
  auto computeS = [&](int buf, f32x16* S) {
#pragma unroll
    for (int t = 0; t < 2; ++t) {
      f32x16 s;
#pragma unroll
      for (int ds = 0; ds < 8; ++ds) {
        const bf16x8 kf = *(const bf16x8*)(sK[buf] + (t * 8 + ds) * 1024 + lane * 16);
        s = MFMA32(kf, qf[ds], (ds == 0) ? Zf : s);
      }
      S[t] = s;
    }
  };

  // exp(S_prev) -> pf (B-fragments for this sub-iter's PV), den accumulate.
  auto doExp = [&](const f32x16* S) {
#pragma unroll
    for (int s = 0; s < 4; ++s) {
      const int t = s >> 1, w = s & 1;
      float e[8];
#pragma unroll
      for (int j = 0; j < 8; ++j) {
        const int rr = w * 4 + (j & 3) + (j >> 2) * 8;
        e[j] = __builtin_amdgcn_exp2f(S[t][rr]);
      }
      den += ((e[0] + e[1]) + (e[2] + e[3])) + ((e[4] + e[5]) + (e[6] + e[7]));
#pragma unroll
      for (int j2 = 0; j2 < 4; ++j2)
        pf[s].u[j2] = pkbf(e[2 * j2], e[2 * j2 + 1]);
    }
  };

  // PV: s=0,1 fragments from LDS (8 ds_read_b128), s=2,3 from vreg (L2,
  // already in flight since iteration top). 16 MFMAs in 4 acc chains.
  auto doPV = [&](int buf) {
    const char* vb = sV[buf] + lane * 16;
#pragma unroll
    for (int s = 0; s < 2; ++s) {
      bf16x8 v0 = *(const bf16x8*)(vb + (s * 4 + 0) * 1024);
      bf16x8 v1 = *(const bf16x8*)(vb + (s * 4 + 1) * 1024);
      bf16x8 v2 = *(const bf16x8*)(vb + (s * 4 + 2) * 1024);
      bf16x8 v3 = *(const bf16x8*)(vb + (s * 4 + 3) * 1024);
      acc[0] = MFMA32(v0, pf[s].v, acc[0]);
      acc[1] = MFMA32(v1, pf[s].v, acc[1]);
      acc[2] = MFMA32(v2, pf[s].v, acc[2]);
      acc[3] = MFMA32(v3, pf[s].v, acc[3]);
    }
#pragma unroll
    for (int s = 2; s < 4; ++s) {
      acc[0] = MFMA32(vreg[(s - 2) * 4 + 0], pf[s].v, acc[0]);
      acc[1] = MFMA32(vreg[(s - 2) * 4 + 1], pf[s].v, acc[1]);
      acc[2] = MFMA32(vreg[(s - 2) * 4 + 2], pf[s].v, acc[2]);
      acc[3] = MFMA32(vreg[(s - 2) * 4 + 3], pf[s].v, acc[3]);
    }
  };

  // ---- pipelined K-loop ----------------------------------------------------
  // iter it: {sync; stageK(it+1); stageV(it); loadV23(it-1);
  //           S(it) || exp(S(it-1)); PV(it-1)}
  stageK(0, 0);
  stageV(0, 0);
  __syncthreads();            // K0, V0(s01) landed
  stageK(1, 1);
  computeS(0, Sa);            // S(0)

  // iter 1 (peeled):
  __syncthreads();            // K1 landed; tile-0 ds_reads drained
  stageK(2, 0);
  stageV(1, 1);
  loadV23(0);
  __builtin_amdgcn_s_setprio(1);
  computeS(1, Sb);            // S(1)
  doExp(Sa);                  // pf <- exp(S(0))
  doPV(0);                    // V(0): s01 from sV[0], s23 from vreg
  __builtin_amdgcn_s_setprio(0);

  for (int itp = 2; itp < nIter; itp += 2) {
    // ---- even iter itp: cur -> Sa, prev = Sb, PV(itp-1) from sV[1]+vreg ----
    __syncthreads();          // K(itp), V(itp-1) landed; old reads drained
    stageK(itp + 1, 1);
    stageV(itp, 0);
    loadV23(itp - 1);
    __builtin_amdgcn_s_setprio(1);
    computeS(0, Sa);
    doExp(Sb);                // pf <- exp(S(itp-1))
    doPV(1);
    __builtin_amdgcn_s_setprio(0);

    // ---- odd iter itp+1: cur -> Sb, prev = Sa, PV(itp) from sV[0]+vreg ----
    __syncthreads();          // K(itp+1), V(itp) landed
    if (itp + 2 < nIter) stageK(itp + 2, 0);
    stageV(itp + 1, 1);
    loadV23(itp);
    __builtin_amdgcn_s_setprio(1);
    computeS(1, Sb);
    doExp(Sa);                // pf <- exp(S(itp))
    doPV(0);
    __builtin_amdgcn_s_setprio(0);
  }

  // drain: V(nIter-1) s01 staged at iter nIter-1; barrier to land it.
  __syncthreads();
  loadV23(nIter - 1);
  doExp(Sb);                  // pf <- exp(S(nIter-1)); covers part of L2 lat
  doPV(1);                    // (nIter-1) odd -> sV[1]

  den += __shfl_xor(den, 32);
  const float rd = 1.0f / den;

  // ---- epilogue: per-wave LDS transpose (XOR-swizzled), coalesced stores ---
  __syncthreads();            // all waves done with sK/sV
  float* wls = (float*)(&sK[0][0] + wave * 4096);   // 32 q-rows x 32 floats
#pragma unroll
  for (int db2 = 0; db2 < 4; ++db2) {
#pragma unroll
    for (int qd = 0; qd < 4; ++qd) {
      float4 v;
      v.x = acc[db2][qd * 4 + 0] * rd;
      v.y = acc[db2][qd * 4 + 1] * rd;
      v.z = acc[db2][qd * 4 + 2] * rd;
      v.w = acc[db2][qd * 4 + 3] * rd;
      *(float4*)(wls + c32 * 32 + (((h5 + 2 * qd) ^ (c32 & 7)) << 2)) = v;
    }
#pragma unroll
    for (int p = 0; p < 4; ++p) {
      const int ql = p * 8 + (lane >> 3);
      const int x = lane & 7;
      const float4 v = *(const float4*)(wls + ql * 32 + ((x ^ (ql & 7)) << 2));
      *(float4*)(out + (size_t)(qrow0 + ql) * 128 + db2 * 32 + x * 4) = v;
    }
  }
}

// ---------------------------------------------------------------------------
extern "C" void kernel_launch(void* const* d_in, const int* in_sizes, int n_in,
                              void* d_out, int out_size, void* d_ws, size_t ws_size,
                              hipStream_t stream) {
  const float* q = (const float*)d_in[0];
  const float* k = (const float*)d_in[1];
  const int N = in_sizes[0] / 128;   // 65536
  const int K = in_sizes[1] / 128;   // 4096
  char* ws = (char*)d_ws;
  char* knf = ws;                          // K*256 B = 1 MB
  char* vtf = ws + (size_t)K * 256;        // 1 MB
  float* out = (float*)d_out;

  prep_k<<<dim3(K / 32), dim3(256), 0, stream>>>(k, knf, vtf, K);
  attn_main<<<dim3(N / 128), dim3(256), 0, stream>>>(q, knf, vtf, out, K);
}